// Round 6
// baseline (267.321 us; speedup 1.0000x reference)
//
#include <hip/hip_runtime.h>
#include <hip/hip_cooperative_groups.h>
#include <math.h>

namespace cg = cooperative_groups;

// RWKV WKV forward v6: single fused cooperative kernel.
// Phase A: per-(b,chunk) aggregates -> agg4[b][h][c] (transposed, coalesced for scan)
// Phase B: wave-parallel exclusive scan over chunks per (b,h) -> st4[b][h][c]
// Phase C: replay chunks from incoming state, nontemporal out stores.
// ws: agg4, st4 = 2 arrays of B*H*NC float4.

#define B_   8
#define T_   2048
#define H_   768
#define HV4_ (H_ / 4)
#define TPB_ 192
#define CUS_ 256

typedef float v4f __attribute__((ext_vector_type(4)));

struct S3 { float a, b, e; };

// fold state x (earlier) through a segment of aggregate y spanning wLen = w*len
__device__ __forceinline__ S3 comb(const S3 x, const S3 y, float wLen) {
    const float e1 = x.e + wLen;
    const float m  = fmaxf(e1, y.e);
    const float p  = __expf(e1 - m);
    const float q  = __expf(y.e - m);
    S3 r;
    r.a = fmaf(x.a, p, y.a * q);
    r.b = fmaf(x.b, p, y.b * q);
    r.e = m;
    return r;
}

__device__ __forceinline__ float rcp_f(float x) { return __builtin_amdgcn_rcpf(x); }

// ---------------- Phase A ----------------
template <int NC>
__device__ __forceinline__ void phaseA(
    const float* __restrict__ key, const float* __restrict__ val,
    const float* __restrict__ td, float4* __restrict__ agg4,
    int b, int c, int tid)
{
    constexpr int L = T_ / NC;
    constexpr int D = 4;
    const int h0 = tid * 4;
    const float4 tdv = *(const float4*)(td + h0);
    const float w[4] = { -__expf(tdv.x), -__expf(tdv.y), -__expf(tdv.z), -__expf(tdv.w) };

    const size_t base = ((size_t)b * T_ + (size_t)c * L) * HV4_ + tid;
    const float4* kp = (const float4*)key + base;
    const float4* vp = (const float4*)val + base;

    float4 kbuf[D], vbuf[D];
#pragma unroll
    for (int i = 0; i < D; ++i) { kbuf[i] = kp[(size_t)i * HV4_]; vbuf[i] = vp[(size_t)i * HV4_]; }

    float a[4] = {0.f,0.f,0.f,0.f}, bb[4] = {0.f,0.f,0.f,0.f};
    float e[4] = {-INFINITY,-INFINITY,-INFINITY,-INFINITY};

#pragma unroll
    for (int t = 0; t < L; ++t) {
        const float4 kt = kbuf[t & (D-1)], vt = vbuf[t & (D-1)];
        if (t + D < L) {
            kbuf[t & (D-1)] = kp[(size_t)(t+D) * HV4_];
            vbuf[t & (D-1)] = vp[(size_t)(t+D) * HV4_];
        }
        const float kk[4] = {kt.x,kt.y,kt.z,kt.w}, vv[4] = {vt.x,vt.y,vt.z,vt.w};
#pragma unroll
        for (int j = 0; j < 4; ++j) {
            const float ew = e[j] + w[j];
            const float m2 = fmaxf(ew, kk[j]);
            const float s1 = __expf(ew - m2);
            const float s2 = __expf(kk[j] - m2);
            a[j]  = fmaf(s1, a[j],  s2 * vv[j]);
            bb[j] = fmaf(s1, bb[j], s2);
            e[j]  = m2;
        }
    }
#pragma unroll
    for (int j = 0; j < 4; ++j)
        agg4[((size_t)b * H_ + h0 + j) * NC + c] = make_float4(a[j], bb[j], e[j], 0.f);
}

// ---------------- Phase B: one wave scans NC chunks of one (b,h) ----------------
template <int NC>
__device__ __forceinline__ void phaseB(
    const float4* __restrict__ agg4, float4* __restrict__ st4,
    const float* __restrict__ td, int s, int lane)
{
    constexpr int L = T_ / NC;
    constexpr int CPL = NC / 64;          // chunks per lane (1 or 2)
    const int b = s / H_;
    const int h = s - b * H_;
    const float wL = -__expf(td[h]) * (float)L;
    const float wP = wL * (float)CPL;
    const size_t rb = ((size_t)b * H_ + h) * NC;

    S3 x[CPL];
#pragma unroll
    for (int i = 0; i < CPL; ++i) {
        const float4 t = agg4[rb + lane * CPL + i];
        x[i].a = t.x; x[i].b = t.y; x[i].e = t.z;
    }
    S3 p = x[0];
    if (CPL == 2) p = comb(x[0], x[CPL-1], wL);

    // inclusive Hillis-Steele scan across 64 lanes
    S3 incl = p;
#pragma unroll
    for (int d = 1; d < 64; d <<= 1) {
        S3 o;
        o.a = __shfl_up(incl.a, d);
        o.b = __shfl_up(incl.b, d);
        o.e = __shfl_up(incl.e, d);
        const S3 t = comb(o, incl, wP * (float)d);
        if (lane >= d) incl = t;
    }
    // exclusive prefix
    S3 excl;
    excl.a = __shfl_up(incl.a, 1);
    excl.b = __shfl_up(incl.b, 1);
    excl.e = __shfl_up(incl.e, 1);
    if (lane == 0) { excl.a = 0.f; excl.b = 0.f; excl.e = -INFINITY; }

    st4[rb + lane * CPL] = make_float4(excl.a, excl.b, excl.e, 0.f);
    if (CPL == 2) {
        const S3 in1 = comb(excl, x[0], wL);
        st4[rb + lane * CPL + 1] = make_float4(in1.a, in1.b, in1.e, 0.f);
    }
}

// ---------------- Phase C ----------------
template <int NC>
__device__ __forceinline__ void phaseC(
    const float* __restrict__ key, const float* __restrict__ val,
    const float* __restrict__ td, const float* __restrict__ tf,
    const float4* __restrict__ st4, float* __restrict__ out,
    int b, int c, int tid)
{
    constexpr int L = T_ / NC;
    constexpr int D = 4;
    const int h0 = tid * 4;
    const float4 tdv = *(const float4*)(td + h0);
    const float4 tfv = *(const float4*)(tf + h0);
    const float w[4] = { -__expf(tdv.x), -__expf(tdv.y), -__expf(tdv.z), -__expf(tdv.w) };
    const float u[4] = { tfv.x, tfv.y, tfv.z, tfv.w };

    float a[4], bb[4], e[4];
#pragma unroll
    for (int j = 0; j < 4; ++j) {
        const float4 s = st4[((size_t)b * H_ + h0 + j) * NC + c];
        a[j] = s.x; bb[j] = s.y; e[j] = s.z;
    }

    const size_t base = ((size_t)b * T_ + (size_t)c * L) * HV4_ + tid;
    const float4* kp = (const float4*)key + base;
    const float4* vp = (const float4*)val + base;
    float4*       op = (float4*)out + base;

    float4 kbuf[D], vbuf[D];
#pragma unroll
    for (int i = 0; i < D; ++i) { kbuf[i] = kp[(size_t)i * HV4_]; vbuf[i] = vp[(size_t)i * HV4_]; }

#pragma unroll
    for (int t = 0; t < L; ++t) {
        const float4 kt = kbuf[t & (D-1)], vt = vbuf[t & (D-1)];
        if (t + D < L) {
            kbuf[t & (D-1)] = kp[(size_t)(t+D) * HV4_];
            vbuf[t & (D-1)] = vp[(size_t)(t+D) * HV4_];
        }
        const float kk[4] = {kt.x,kt.y,kt.z,kt.w}, vv[4] = {vt.x,vt.y,vt.z,vt.w};
        float o[4];
#pragma unroll
        for (int j = 0; j < 4; ++j) {
            const float uk = u[j] + kk[j];
            const float m1 = fmaxf(e[j], uk);
            const float wt = __expf(uk - m1);
            const float sc = __expf(e[j] - m1);
            o[j] = fmaf(a[j], sc, wt * vv[j]) * rcp_f(fmaf(bb[j], sc, wt));

            const float ew = e[j] + w[j];
            const float m2 = fmaxf(ew, kk[j]);
            const float s1 = __expf(ew - m2);
            const float s2 = __expf(kk[j] - m2);
            a[j]  = fmaf(s1, a[j],  s2 * vv[j]);
            bb[j] = fmaf(s1, bb[j], s2);
            e[j]  = m2;
        }
        v4f ov = { o[0], o[1], o[2], o[3] };
        __builtin_nontemporal_store(ov, (v4f*)&op[(size_t)t * HV4_]);
    }
}

// MODE: 0 = fused cooperative, 1 = A only, 2 = B only, 3 = C only
template <int NC, int MODE>
__global__ __launch_bounds__(TPB_, 3) void wkv_kern(
    const float* __restrict__ key, const float* __restrict__ val,
    const float* __restrict__ td, const float* __restrict__ tf,
    float4* __restrict__ agg4, float4* __restrict__ st4,
    float* __restrict__ out)
{
    constexpr int NT = B_ * NC;
    const int tid = threadIdx.x;

    if (MODE == 0 || MODE == 1) {
        for (int tile = blockIdx.x; tile < NT; tile += gridDim.x)
            phaseA<NC>(key, val, td, agg4, tile / NC, tile % NC, tid);
    }
    if (MODE == 0) cg::this_grid().sync();
    if (MODE == 0 || MODE == 2) {
        const int nw   = gridDim.x * (TPB_ / 64);
        const int wid  = blockIdx.x * (TPB_ / 64) + (tid >> 6);
        const int lane = tid & 63;
        for (int s = wid; s < B_ * H_; s += nw)
            phaseB<NC>(agg4, st4, td, s, lane);
    }
    if (MODE == 0) cg::this_grid().sync();
    if (MODE == 0 || MODE == 3) {
        for (int tile = blockIdx.x; tile < NT; tile += gridDim.x)
            phaseC<NC>(key, val, td, tf, st4, out, tile / NC, tile % NC, tid);
    }
}

// ---------------- launcher ----------------
template <int NC>
static void launch_nc(const float* key, const float* val, const float* td,
                      const float* tf, float* out, void* ws, hipStream_t stream)
{
    constexpr int NT = B_ * NC;
    float4* agg4 = (float4*)ws;
    float4* st4  = agg4 + (size_t)B_ * H_ * NC;

    int maxB = 0;
    hipError_t qerr = hipOccupancyMaxActiveBlocksPerMultiprocessor(
        &maxB, wkv_kern<NC, 0>, TPB_, 0);
    if (qerr == hipSuccess && maxB > 0) {
        int nblk = maxB * CUS_;
        if (nblk > NT) nblk = NT;
        void* args[7] = { (void*)&key, (void*)&val, (void*)&td, (void*)&tf,
                          (void*)&agg4, (void*)&st4, (void*)&out };
        hipError_t lerr = hipLaunchCooperativeKernel(
            reinterpret_cast<void*>(wkv_kern<NC, 0>), dim3(nblk), dim3(TPB_),
            args, 0, stream);
        if (lerr == hipSuccess) return;
    }
    // fallback: 3 sequential non-cooperative launches
    wkv_kern<NC, 1><<<dim3(NT), dim3(TPB_), 0, stream>>>(key, val, td, tf, agg4, st4, out);
    wkv_kern<NC, 2><<<dim3((B_ * H_) / (TPB_ / 64)), dim3(TPB_), 0, stream>>>(key, val, td, tf, agg4, st4, out);
    wkv_kern<NC, 3><<<dim3(NT), dim3(TPB_), 0, stream>>>(key, val, td, tf, agg4, st4, out);
}

extern "C" void kernel_launch(void* const* d_in, const int* in_sizes, int n_in,
                              void* d_out, int out_size, void* d_ws, size_t ws_size,
                              hipStream_t stream) {
    const float* key = (const float*)d_in[0];
    const float* val = (const float*)d_in[1];
    const float* td  = (const float*)d_in[2];
    const float* tf  = (const float*)d_in[3];
    float* out = (float*)d_out;

    const size_t need128 = (size_t)2 * B_ * H_ * 128 * sizeof(float4); // 25.2 MB
    if (ws_size >= need128) launch_nc<128>(key, val, td, tf, out, d_ws, stream);
    else                    launch_nc<64>(key, val, td, tf, out, d_ws, stream);
}